// Round 1
// baseline (131.407 us; speedup 1.0000x reference)
//
#include <hip/hip_runtime.h>

#define IMH 1024
#define IMW 1024
#define GD 8
#define GH 16
#define GW 16
#define NC 12

__global__ __launch_bounds__(256) void bsa_kernel(
    const float* __restrict__ grid,
    const float* __restrict__ guide,
    const float* __restrict__ image,
    float* __restrict__ out)
{
    const int y = blockIdx.x;
    const int b = blockIdx.y;

    // y-lerped grid, layout [z][x][c] so the 12 coeffs are contiguous (3 float4s)
    __shared__ __align__(16) float sG[GD][GW][NC];   // 6 KB

    const float gy  = (y + 0.5f) * ((float)GH / IMH);
    const float fyf = floorf(gy - 0.5f);
    const float ty  = gy - 0.5f - fyf;
    const int   fy  = (int)fyf;
    const int   iy0 = min(GH - 1, max(0, fy));
    const int   iy1 = min(GH - 1, max(0, fy + 1));

    const float* gb = grid + (size_t)b * NC * GD * GH * GW;
    for (int i = threadIdx.x; i < GD * GW * NC; i += 256) {
        const int c = i % NC;
        const int x = (i / NC) % GW;
        const int z = i / (NC * GW);
        const float v0 = gb[((c * GD + z) * GH + iy0) * GW + x];
        const float v1 = gb[((c * GD + z) * GH + iy1) * GW + x];
        sG[z][x][c] = v0 + ty * (v1 - v0);
    }
    __syncthreads();

    const int x0 = threadIdx.x * 4;
    const size_t plane = (size_t)IMH * IMW;

    const float* gp = guide + ((size_t)b * IMH + y) * IMW + x0;
    const float* ip = image + ((size_t)b * 3 * IMH + y) * IMW + x0;

    const float4 gv = *(const float4*)gp;
    const float4 ir = *(const float4*)(ip);
    const float4 ig = *(const float4*)(ip + plane);
    const float4 ib = *(const float4*)(ip + 2 * plane);

    const float gvals[4] = {gv.x, gv.y, gv.z, gv.w};
    const float rv[4]    = {ir.x, ir.y, ir.z, ir.w};
    const float gv2[4]   = {ig.x, ig.y, ig.z, ig.w};
    const float bv[4]    = {ib.x, ib.y, ib.z, ib.w};

    float o0[4], o1[4], o2[4];

#pragma unroll
    for (int p = 0; p < 4; ++p) {
        const int x = x0 + p;
        const float gx  = (x + 0.5f) * ((float)GW / IMW);
        const float fxf = floorf(gx - 0.5f);
        const float tx  = gx - 0.5f - fxf;
        const int   fx  = (int)fxf;
        const int   ix0 = min(GW - 1, max(0, fx));
        const int   ix1 = min(GW - 1, max(0, fx + 1));

        const float gz  = gvals[p] * (float)GD;
        const float fzf = floorf(gz - 0.5f);
        const float tz  = gz - 0.5f - fzf;
        const int   fzi = (int)fzf;
        const int   iz0 = min(GD - 1, max(0, fzi));
        const int   iz1 = min(GD - 1, max(0, fzi + 1));

        const float w00 = (1.0f - tz) * (1.0f - tx);
        const float w01 = (1.0f - tz) * tx;
        const float w10 = tz * (1.0f - tx);
        const float w11 = tz * tx;

        const float* p00 = &sG[iz0][ix0][0];
        const float* p01 = &sG[iz0][ix1][0];
        const float* p10 = &sG[iz1][ix0][0];
        const float* p11 = &sG[iz1][ix1][0];

        float res[3];
#pragma unroll
        for (int i = 0; i < 3; ++i) {
            const float4 a = *(const float4*)(p00 + 4 * i);
            const float4 c = *(const float4*)(p01 + 4 * i);
            const float4 d = *(const float4*)(p10 + 4 * i);
            const float4 e = *(const float4*)(p11 + 4 * i);
            const float c0 = w00 * a.x + w01 * c.x + w10 * d.x + w11 * e.x;
            const float c1 = w00 * a.y + w01 * c.y + w10 * d.y + w11 * e.y;
            const float c2 = w00 * a.z + w01 * c.z + w10 * d.z + w11 * e.z;
            const float c3 = w00 * a.w + w01 * c.w + w10 * d.w + w11 * e.w;
            res[i] = c0 * rv[p] + c1 * gv2[p] + c2 * bv[p] + c3;
        }
        o0[p] = res[0];
        o1[p] = res[1];
        o2[p] = res[2];
    }

    float* op = out + ((size_t)b * 3 * IMH + y) * IMW + x0;
    *(float4*)(op)             = make_float4(o0[0], o0[1], o0[2], o0[3]);
    *(float4*)(op + plane)     = make_float4(o1[0], o1[1], o1[2], o1[3]);
    *(float4*)(op + 2 * plane) = make_float4(o2[0], o2[1], o2[2], o2[3]);
}

extern "C" void kernel_launch(void* const* d_in, const int* in_sizes, int n_in,
                              void* d_out, int out_size, void* d_ws, size_t ws_size,
                              hipStream_t stream) {
    const float* grid  = (const float*)d_in[0];
    const float* guide = (const float*)d_in[1];
    const float* image = (const float*)d_in[2];
    float* out = (float*)d_out;

    const int B = in_sizes[1] / (IMH * IMW);   // guide is (B, H, W)
    dim3 g(IMH, B);
    bsa_kernel<<<g, 256, 0, stream>>>(grid, guide, image, out);
}

// Round 2
// 118.822 us; speedup vs baseline: 1.1059x; 1.1059x over previous
//
#include <hip/hip_runtime.h>

#define IMH 1024
#define IMW 1024
#define GD 8
#define GH 16
#define GW 16
#define NC 12

// Layout rationale: sG[x][z][c] — x-stride 96 floats (== 0 mod 32 banks),
// z-stride 12 floats. Bank of a gather = (12*z + c) mod 32: distinct z ->
// distinct bank (12z mod 32 hits 0,12,24,4,16,28,8,20 — all distinct).
// Pixel mapping x = tid + 256*p keeps each wave inside one 64-aligned span
// -> <=2 distinct ix per read -> <=2-way conflicts (free on gfx950).
__global__ __launch_bounds__(256) void bsa_kernel(
    const float* __restrict__ grid,
    const float* __restrict__ guide,
    const float* __restrict__ image,
    float* __restrict__ out)
{
    const int y = blockIdx.x;
    const int b = blockIdx.y;

    __shared__ __align__(16) float sG[GW][GD][NC];   // 6 KB, [x][z][c]

    const float gy  = (y + 0.5f) * ((float)GH / IMH);
    const float fyf = floorf(gy - 0.5f);
    const float ty  = gy - 0.5f - fyf;
    const int   fy  = (int)fyf;
    const int   iy0 = min(GH - 1, max(0, fy));
    const int   iy1 = min(GH - 1, max(0, fy + 1));

    const float* gb = grid + (size_t)b * NC * GD * GH * GW;
    // i -> x fastest (coalesced global reads); LDS write conflicts here are
    // a one-time ~1K cycle cost per block, negligible.
    for (int i = threadIdx.x; i < GD * GW * NC; i += 256) {
        const int x = i & (GW - 1);
        const int z = (i >> 4) & (GD - 1);
        const int c = i >> 7;
        const float v0 = gb[((c * GD + z) * GH + iy0) * GW + x];
        const float v1 = gb[((c * GD + z) * GH + iy1) * GW + x];
        sG[x][z][c] = v0 + ty * (v1 - v0);
    }
    __syncthreads();

    const size_t plane = (size_t)IMH * IMW;
    const float* gp = guide + ((size_t)b * IMH + y) * IMW;
    const float* ip = image + ((size_t)b * 3 * IMH + y) * IMW;
    float*       op = out   + ((size_t)b * 3 * IMH + y) * IMW;

#pragma unroll
    for (int p = 0; p < 4; ++p) {
        const int x = threadIdx.x + 256 * p;

        const float gv = gp[x];
        const float rv = ip[x];
        const float g2 = ip[x + plane];
        const float bv = ip[x + 2 * plane];

        const float gx  = (x + 0.5f) * ((float)GW / IMW);
        const float fxf = floorf(gx - 0.5f);
        const float tx  = gx - 0.5f - fxf;
        const int   fx  = (int)fxf;
        const int   ix0 = min(GW - 1, max(0, fx));
        const int   ix1 = min(GW - 1, max(0, fx + 1));

        const float gz  = gv * (float)GD;
        const float fzf = floorf(gz - 0.5f);
        const float tz  = gz - 0.5f - fzf;
        const int   fzi = (int)fzf;
        const int   iz0 = min(GD - 1, max(0, fzi));
        const int   iz1 = min(GD - 1, max(0, fzi + 1));

        const float w00 = (1.0f - tz) * (1.0f - tx);   // (iz0, ix0)
        const float w01 = (1.0f - tz) * tx;            // (iz0, ix1)
        const float w10 = tz * (1.0f - tx);            // (iz1, ix0)
        const float w11 = tz * tx;                     // (iz1, ix1)

        const float* p00 = &sG[ix0][iz0][0];
        const float* p01 = &sG[ix1][iz0][0];
        const float* p10 = &sG[ix0][iz1][0];
        const float* p11 = &sG[ix1][iz1][0];

        float res[3];
#pragma unroll
        for (int i = 0; i < 3; ++i) {
            const float4 a = *(const float4*)(p00 + 4 * i);
            const float4 c = *(const float4*)(p01 + 4 * i);
            const float4 d = *(const float4*)(p10 + 4 * i);
            const float4 e = *(const float4*)(p11 + 4 * i);
            const float c0 = w00 * a.x + w01 * c.x + w10 * d.x + w11 * e.x;
            const float c1 = w00 * a.y + w01 * c.y + w10 * d.y + w11 * e.y;
            const float c2 = w00 * a.z + w01 * c.z + w10 * d.z + w11 * e.z;
            const float c3 = w00 * a.w + w01 * c.w + w10 * d.w + w11 * e.w;
            res[i] = c0 * rv + c1 * g2 + c2 * bv + c3;
        }

        op[x]             = res[0];
        op[x + plane]     = res[1];
        op[x + 2 * plane] = res[2];
    }
}

extern "C" void kernel_launch(void* const* d_in, const int* in_sizes, int n_in,
                              void* d_out, int out_size, void* d_ws, size_t ws_size,
                              hipStream_t stream) {
    const float* grid  = (const float*)d_in[0];
    const float* guide = (const float*)d_in[1];
    const float* image = (const float*)d_in[2];
    float* out = (float*)d_out;

    const int B = in_sizes[1] / (IMH * IMW);   // guide is (B, H, W)
    dim3 g(IMH, B);
    bsa_kernel<<<g, 256, 0, stream>>>(grid, guide, image, out);
}